// Round 11
// baseline (135.737 us; speedup 1.0000x reference)
//
#include <hip/hip_runtime.h>
#include <math.h>

#define DEV static __device__ __forceinline__

constexpr float MIN_NORM = 1e-15f;
constexpr float BALL_EPS = 1e-5f;
constexpr int D = 512;          // feature dim (fixed by problem)

typedef float f32x4 __attribute__((ext_vector_type(4)));
typedef short short8v __attribute__((ext_vector_type(8)));
typedef unsigned short ushort8v __attribute__((ext_vector_type(8)));

DEV float rcpf_(float x) { return __builtin_amdgcn_rcpf(x); }
DEV float rsqf_(float x) { return __builtin_amdgcn_rsqf(x); }

// tanh(a)/a for a >= 0
DEV float tanh_over_a_pos(float a) {
    const float e = __expf(-2.0f * a);
    return (1.0f - e) * rcpf_((1.0f + e) * fmaxf(a, 1e-20f));
}

// bf16 split helpers (RNE)
DEV unsigned short f2bf(float f) {
    unsigned int u = __float_as_uint(f);
    u = (u + 0x7FFFu + ((u >> 16) & 1u)) >> 16;
    return (unsigned short)u;
}
DEV float bf2f(unsigned short h) { return __uint_as_float(((unsigned int)h) << 16); }

// Packed panel layout (exact LDS image; staging is a linear copy):
//   pack[kb][row][slot], kb = K-tile (32 K-elems), slot = 16B chunk 0..7.
//   chunks 0-3 = hi k-sub 0..3, 4-7 = lo. Stored slot = chunk ^ (row & 7).
DEV void write_packed_row(unsigned short* pack, size_t nrow, int row,
                          int lane, ushort8v hi, ushort8v lo)
{
    const int kb  = lane >> 2;
    const int cch = lane & 3;
    const int rx  = row & 7;
    unsigned short* dst = pack + ((size_t)kb * nrow + row) * 64;   // 128B rows
    *(ushort8v*)(dst + ((cch ^ rx) * 8))       = hi;
    *(ushort8v*)(dst + (((cch + 4) ^ rx) * 8)) = lo;
}

// ---------------------------------------------------------------------------
// Merged prep kernel: 4 ROWS PER WAVE, all 20 row-loads hoisted -> 2x the
// in-flight bytes per wave (kernel is latency-bound: VALUBusy 20%, HBM 32%).
// 256 threads = 4 waves = 16 rows/block.
// ---------------------------------------------------------------------------
__global__ __launch_bounds__(256)
void prep_kernel(const float* __restrict__ head,
                 const float* __restrict__ rel,
                 const float* __restrict__ rel_diag,
                 const float* __restrict__ curvature,
                 const float* __restrict__ context,
                 const float* __restrict__ scale_p,
                 const float* __restrict__ tail,
                 unsigned short* __restrict__ packA,
                 unsigned short* __restrict__ packB,
                 float* __restrict__ row_x2,
                 float* __restrict__ row_c,
                 float* __restrict__ row_sc,
                 float* __restrict__ vnorm,
                 int B, int T)
{
    const int lane = threadIdx.x & 63;
    const int base = lane * 8;
    const int wid  = blockIdx.x * 4 + (threadIdx.x >> 6);
    const int r0   = wid * 4;                       // first of 4 rows

    if (r0 >= B) {
        // ---- tail path: 4 rows, loads hoisted ----
        const int tr = r0 - B;
        float v[4][8];
#pragma unroll
        for (int rr = 0; rr < 4; ++rr) {
            const size_t off = (size_t)(tr + rr) * D + base;
            *(float4*)&v[rr][0] = *(const float4*)(tail + off);
            *(float4*)&v[rr][4] = *(const float4*)(tail + off + 4);
        }
        float s[4] = {0.f, 0.f, 0.f, 0.f};
        ushort8v hi[4], lo[4];
#pragma unroll
        for (int rr = 0; rr < 4; ++rr)
#pragma unroll
            for (int e = 0; e < 8; ++e) {
                s[rr] += v[rr][e] * v[rr][e];
                const unsigned short hb_ = f2bf(v[rr][e]);
                hi[rr][e] = hb_;
                lo[rr][e] = f2bf(v[rr][e] - bf2f(hb_));
            }
#pragma unroll
        for (int o = 32; o > 0; o >>= 1)
#pragma unroll
            for (int rr = 0; rr < 4; ++rr)
                s[rr] += __shfl_xor(s[rr], o, 64);
#pragma unroll
        for (int rr = 0; rr < 4; ++rr) {
            write_packed_row(packB, (size_t)T, tr + rr, lane, hi[rr], lo[rr]);
            if (lane == 0) vnorm[tr + rr] = sqrtf(s[rr]);
        }
        return;
    }

    // ---- head path: 4 rows, all loads hoisted, chains interleaved ----
    float hv[4][8], rv[4][8], gv[4][8], fv[4][8], cxv[4][8];
#pragma unroll
    for (int rr = 0; rr < 4; ++rr) {
        const size_t roff = (size_t)(r0 + rr) * D + base;
        const size_t doff = (size_t)(r0 + rr) * 2 * D + base;
        *(float4*)&hv[rr][0]  = *(const float4*)(head + roff);
        *(float4*)&hv[rr][4]  = *(const float4*)(head + roff + 4);
        *(float4*)&rv[rr][0]  = *(const float4*)(rel + roff);
        *(float4*)&rv[rr][4]  = *(const float4*)(rel + roff + 4);
        *(float4*)&gv[rr][0]  = *(const float4*)(rel_diag + doff);
        *(float4*)&gv[rr][4]  = *(const float4*)(rel_diag + doff + 4);
        *(float4*)&fv[rr][0]  = *(const float4*)(rel_diag + doff + D);
        *(float4*)&fv[rr][4]  = *(const float4*)(rel_diag + doff + D + 4);
        *(float4*)&cxv[rr][0] = *(const float4*)(context + roff);
        *(float4*)&cxv[rr][4] = *(const float4*)(context + roff + 4);
    }

    float rq[4][8], rf[4][8];
#pragma unroll
    for (int rr = 0; rr < 4; ++rr)
#pragma unroll
        for (int p = 0; p < 4; ++p) {
            const float x0 = hv[rr][2*p], x1 = hv[rr][2*p+1];
            float g0 = gv[rr][2*p], g1 = gv[rr][2*p+1];
            const float gi = rsqf_(fmaxf(g0*g0 + g1*g1, 1e-30f));
            g0 *= gi; g1 *= gi;
            rq[rr][2*p]   = g0*x0 - g1*x1;       // rotation
            rq[rr][2*p+1] = g0*x1 + g1*x0;
            float f0 = fv[rr][2*p], f1 = fv[rr][2*p+1];
            const float fi = rsqf_(fmaxf(f0*f0 + f1*f1, 1e-30f));
            f0 *= fi; f1 *= fi;
            rf[rr][2*p]   = f0*x0 + f1*x1;       // reflection
            rf[rr][2*p+1] = f1*x0 - f0*x1;
        }

    float s[4][8];
#pragma unroll
    for (int rr = 0; rr < 4; ++rr) {
#pragma unroll
        for (int k = 0; k < 8; ++k) s[rr][k] = 0.f;
#pragma unroll
        for (int e = 0; e < 8; ++e) {
            s[rr][0] += cxv[rr][e]*rf[rr][e];   s[rr][1] += cxv[rr][e]*rq[rr][e];
            s[rr][2] += rv[rr][e]*rv[rr][e];    s[rr][3] += rf[rr][e]*rv[rr][e];
            s[rr][4] += rq[rr][e]*rv[rr][e];    s[rr][5] += rf[rr][e]*rf[rr][e];
            s[rr][6] += rq[rr][e]*rq[rr][e];    s[rr][7] += rf[rr][e]*rq[rr][e];
        }
    }
    // 32 interleaved butterfly chains
#pragma unroll
    for (int o = 32; o > 0; o >>= 1)
#pragma unroll
        for (int rr = 0; rr < 4; ++rr)
#pragma unroll
            for (int k = 0; k < 8; ++k)
                s[rr][k] += __shfl_xor(s[rr][k], o, 64);

    const float sc = scale_p[0];
    float pre[4][8], r2p[4];
    float cS[4], sqcS[4];
#pragma unroll
    for (int rr = 0; rr < 4; ++rr) {
        const float cu = curvature[r0 + rr];
        const float c  = fmaxf(cu, 0.0f) + __logf(1.0f + __expf(-fabsf(cu)));
        const float sqc = sqrtf(c);
        cS[rr] = c; sqcS[rr] = sqc;

        const float a0 = s[rr][0] * sc, a1 = s[rr][1] * sc;
        const float mx = fmaxf(a0, a1);
        const float e0 = __expf(a0 - mx), e1 = __expf(a1 - mx);
        const float w0 = e0 * rcpf_(e0 + e1);
        const float w1 = 1.0f - w0;

        const float att2    = fmaxf(w0*w0*s[rr][5] + 2.0f*w0*w1*s[rr][7] + w1*w1*s[rr][6], 0.0f);
        const float attdrel = w0*s[rr][3] + w1*s[rr][4];
        const float u_att = fmaxf(sqrtf(att2), MIN_NORM);
        const float u_rel = fmaxf(sqrtf(s[rr][2]), MIN_NORM);

        const float kl = tanh_over_a_pos(sqc * u_att);
        const float kr = tanh_over_a_pos(sqc * u_rel);

        const float x2 = kl*kl*att2;
        const float y2 = kr*kr*s[rr][2];
        const float xy = kl*kr*attdrel;

        const float Am  = 1.0f + 2.0f*c*xy + c*y2;
        const float Bm  = 1.0f - c*x2;
        const float inv_den = rcpf_(fmaxf(1.0f + 2.0f*c*xy + c*c*x2*y2, MIN_NORM));

        r2p[rr] = 0.f;
#pragma unroll
        for (int e = 0; e < 8; ++e) {
            const float attq = w0*rf[rr][e] + w1*rq[rr][e];
            pre[rr][e] = (Am*kl*attq + Bm*kr*rv[rr][e]) * inv_den;
            r2p[rr] += pre[rr][e]*pre[rr][e];
        }
    }
#pragma unroll
    for (int o = 32; o > 0; o >>= 1)
#pragma unroll
        for (int rr = 0; rr < 4; ++rr)
            r2p[rr] += __shfl_xor(r2p[rr], o, 64);

#pragma unroll
    for (int rr = 0; rr < 4; ++rr) {
        const float nrm  = fmaxf(sqrtf(r2p[rr]), MIN_NORM);
        const float maxn = (1.0f - BALL_EPS) * rcpf_(sqcS[rr]);
        const float psc  = (nrm > maxn) ? (maxn * rcpf_(nrm)) : 1.0f;

        ushort8v hi, lo;
#pragma unroll
        for (int e = 0; e < 8; ++e) {
            const float o = pre[rr][e] * psc;
            const unsigned short hb_ = f2bf(o);
            hi[e] = hb_;
            lo[e] = f2bf(o - bf2f(hb_));
        }
        write_packed_row(packA, (size_t)B, r0 + rr, lane, hi, lo);

        if (lane == 0) {
            row_x2[r0 + rr] = r2p[rr] * psc * psc;
            row_c[r0 + rr]  = cS[rr];
            row_sc[r0 + rr] = sqcS[rr];
        }
    }
}

// ---------------------------------------------------------------------------
// Kernel C: 64x128 tile, 4 waves (wave-tile 64x32, acc 4x2), BK=32 hi|lo
// packed 128B rows, 48KB LDS dbuf -> 3 BLOCKS/CU = 12 waves/CU = 3 waves/SIMD
// (the m97 TLP regime; every prior variant ran 2 waves/SIMD and plateaued at
// ~640 TF regardless of schedule). One vmcnt(0)+barrier per K-step.
// ---------------------------------------------------------------------------
__global__ __launch_bounds__(256, 3)
void score_kernel(const unsigned short* __restrict__ packA,
                  const unsigned short* __restrict__ packB,
                  const float* __restrict__ vnorm,
                  const float* __restrict__ row_x2,
                  const float* __restrict__ row_c,
                  const float* __restrict__ row_sc,
                  const float* __restrict__ head_bias,
                  const float* __restrict__ tail_bias,
                  float* __restrict__ out,
                  int cs, int ns, int nrowA, int nrowB)
{
    __shared__ __align__(16) char smem[2][24576];   // slot: A 8KB | B 16KB

    // XCD-aware remap: nwg=2048, 256 contiguous blocks per XCD (= 2 batches).
    const int orig = blockIdx.x;
    const int wg = (orig & 7) * 256 + (orig >> 3);
    const int bz = wg >> 7;            // batch (2 per XCD)
    const int by = (wg >> 3) & 15;     // M tile (64 rows)
    const int bx = wg & 7;             // N tile (128 cols)
    const int m0 = by * 64;
    const int n0 = bx * 128;

    const int tid  = threadIdx.x;
    const int lane = tid & 63;
    const int wn   = tid >> 6;                    // wave = N column group (0-3)
    const int lrow = lane & 15, lg = lane >> 4;

    f32x4 acc[4][2];
#pragma unroll
    for (int i = 0; i < 4; ++i)
#pragma unroll
        for (int j = 0; j < 2; ++j) acc[i][j] = f32x4{0.f, 0.f, 0.f, 0.f};

    // per-thread constant read bases: row&7 == lrow&7 for all frags
    const int xr = (lg ^ (lrow & 7)) * 16;
    const int baseA = lrow * 128 + xr;                       // A frag m: +m*2048
    const int baseB = 8192 + (wn * 32 + lrow) * 128 + xr;    // B frag n: +n*2048
    // lo chunk = hi byte-offset ^ 64

    const char* gA = (const char*)packA + (size_t)(bz * cs + m0) * 128;
    const char* gB = (const char*)packB + (size_t)(bz * ns + n0) * 128;
    const size_t strA = (size_t)nrowA * 128;   // per-K-tile panel stride
    const size_t strB = (size_t)nrowB * 128;
    const int t16 = tid * 16;

#define GLL(srcp, dstp)                                                        \
    __builtin_amdgcn_global_load_lds(                                          \
        (const __attribute__((address_space(1))) unsigned int*)(srcp),         \
        (__attribute__((address_space(3))) unsigned int*)(dstp), 16, 0, 0)

    // full-tile stage: A 8KB (2 x 4KB) + B 16KB (4 x 4KB), linear copy
#define STAGE_ALL(dstslot, srcA, srcB)                                         \
    do {                                                                       \
        _Pragma("unroll")                                                      \
        for (int p_ = 0; p_ < 2; ++p_) {                                       \
            const int o_ = p_ * 4096 + t16;                                    \
            GLL((srcA) + o_, (dstslot) + o_);                                  \
        }                                                                      \
        _Pragma("unroll")                                                      \
        for (int p_ = 0; p_ < 4; ++p_) {                                       \
            const int o_ = p_ * 4096 + t16;                                    \
            GLL((srcB) + o_, (dstslot) + 8192 + o_);                           \
        }                                                                      \
    } while (0)

#define RD(p, off) (*(const short8v*)((p) + (off)))
#define MFMA_(A_, B_, C_) __builtin_amdgcn_mfma_f32_16x16x32_bf16(A_, B_, C_, 0, 0, 0)
#define BAR()   __builtin_amdgcn_s_barrier()
#define VM0()   asm volatile("s_waitcnt vmcnt(0)" ::: "memory")

    // ---- prologue: tile0 -> slot0 ----
    STAGE_ALL(&smem[0][0], gA, gB);
    VM0();
    BAR();

    short8v ah[4], al[4], bh[2], bl[2];

#pragma unroll 1
    for (int t = 0; t < 16; ++t) {
        char* cur = &smem[t & 1][0];
        char* oth = &smem[(t + 1) & 1][0];

        // stage tile t+1 first (full step of vmcnt cover)
        if (t < 15)
            STAGE_ALL(oth, gA + (size_t)(t + 1) * strA, gB + (size_t)(t + 1) * strB);

        // ---- read all fragments (12 ds_read_b128/lane) ----
#pragma unroll
        for (int m = 0; m < 4; ++m) {
            ah[m] = RD(cur, baseA + m * 2048);
            al[m] = RD(cur, (baseA ^ 64) + m * 2048);
        }
#pragma unroll
        for (int n = 0; n < 2; ++n) {
            bh[n] = RD(cur, baseB + n * 2048);
            bl[n] = RD(cur, (baseB ^ 64) + n * 2048);
        }

        // ---- 24 MFMA, product-major (dep distance 8) ----
#pragma unroll
        for (int m = 0; m < 4; ++m)
#pragma unroll
            for (int n = 0; n < 2; ++n)
                acc[m][n] = MFMA_(ah[m], bh[n], acc[m][n]);
#pragma unroll
        for (int m = 0; m < 4; ++m)
#pragma unroll
            for (int n = 0; n < 2; ++n)
                acc[m][n] = MFMA_(ah[m], bl[n], acc[m][n]);
#pragma unroll
        for (int m = 0; m < 4; ++m)
#pragma unroll
            for (int n = 0; n < 2; ++n)
                acc[m][n] = MFMA_(al[m], bh[n], acc[m][n]);

        // single end-of-step sync: my staging loads for t+1 have landed
        VM0();
        BAR();
    }

    // ---- fused hyperbolic-distance epilogue ----
    // C/D layout (m89-verified): col = lane&15, row = (lane>>4)*4 + q
    const int nbase = n0 + wn * 32 + lrow;
    float rvn[2], vnv[2], tb[2];
#pragma unroll
    for (int j = 0; j < 2; ++j) {
        const int gn = bz * ns + nbase + j * 16;
        const float vn = vnorm[gn];
        vnv[j] = vn;
        rvn[j] = 1.0f / vn;
        tb[j]  = tail_bias[gn];
    }
#pragma unroll
    for (int i = 0; i < 4; ++i) {
#pragma unroll
        for (int q = 0; q < 4; ++q) {
            const int gm = bz * cs + m0 + i * 16 + lg * 4 + q;
            const float x2  = row_x2[gm];
            const float cc  = row_c[gm];
            const float scq = row_sc[gm];
            const float hb  = head_bias[gm];
            const float rscq = 1.0f / scq;
            float* orow = out + (size_t)gm * ns + nbase;
#pragma unroll
            for (int j = 0; j < 2; ++j) {
                const float xv = acc[i][j][q] * rvn[j];
                float xx = fminf(scq * vnv[j], 15.0f);           // x >= 0 always
                const float ey = __expf(2.0f * xx);
                const float g  = (1.0f - 2.0f / (ey + 1.0f)) * rscq;  // tanh/sqc
                const float c1 = 1.0f - 2.0f*cc*g*xv + cc*g*g;
                const float c2 = 1.0f - cc*x2;
                const float num = sqrtf(fmaxf(c1*c1*x2 + c2*c2*g*g - 2.0f*c1*c2*g*xv, 0.0f));
                const float den = fmaxf(1.0f - 2.0f*cc*g*xv + cc*cc*g*g*x2, MIN_NORM);
                float tt = scq * num * __builtin_amdgcn_rcpf(den);
                tt = fminf(tt, 1.0f - 1e-5f);                    // t >= 0 always
                const float ath = 0.5f * __logf((1.0f + tt) * __builtin_amdgcn_rcpf(1.0f - tt));
                const float dist = 2.0f * rscq * ath;
                orow[j * 16] = -dist * dist + hb + tb[j];
            }
        }
    }
#undef GLL
#undef STAGE_ALL
#undef RD
#undef MFMA_
#undef BAR
#undef VM0
}

// ---------------------------------------------------------------------------
extern "C" void kernel_launch(void* const* d_in, const int* in_sizes, int n_in,
                              void* d_out, int out_size, void* d_ws, size_t ws_size,
                              hipStream_t stream)
{
    const float* head      = (const float*)d_in[0];
    const float* head_bias = (const float*)d_in[1];
    const float* rel       = (const float*)d_in[2];
    const float* rel_diag  = (const float*)d_in[3];
    const float* curvature = (const float*)d_in[4];
    const float* context   = (const float*)d_in[5];
    const float* scale     = (const float*)d_in[6];
    const float* tail      = (const float*)d_in[7];
    const float* tail_bias = (const float*)d_in[8];

    const int B  = in_sizes[1];        // 16384
    const int T  = in_sizes[8];        // 16384
    const int ns = out_size / B;       // 1024
    const int nc = T / ns;             // 16
    const int cs = B / nc;             // 1024

    // ws layout: packA (16*B*64 us = 32MB) | packB (32MB) | f32 scalars
    unsigned short* packA = (unsigned short*)d_ws;
    unsigned short* packB = packA + (size_t)16 * B * 64;
    float* row_x2 = (float*)(packB + (size_t)16 * T * 64);
    float* row_c  = row_x2 + B;
    float* row_sc = row_c + B;
    float* vnormb = row_sc + B;

    prep_kernel<<<(B + T) / 16, 256, 0, stream>>>(head, rel, rel_diag, curvature,
                                                  context, scale, tail, packA, packB,
                                                  row_x2, row_c, row_sc, vnormb, B, T);

    const int nblk = (ns / 128) * (cs / 64) * nc;   // 2048
    score_kernel<<<nblk, 256, 0, stream>>>(packA, packB, vnormb, row_x2, row_c,
                                           row_sc, head_bias, tail_bias,
                                           (float*)d_out, cs, ns, B, T);
}

// Round 12
// 125.957 us; speedup vs baseline: 1.0777x; 1.0777x over previous
//
#include <hip/hip_runtime.h>
#include <math.h>

#define DEV static __device__ __forceinline__

constexpr float MIN_NORM = 1e-15f;
constexpr float BALL_EPS = 1e-5f;
constexpr int D = 512;          // feature dim (fixed by problem)

typedef float f32x4 __attribute__((ext_vector_type(4)));
typedef short short8v __attribute__((ext_vector_type(8)));
typedef unsigned short ushort8v __attribute__((ext_vector_type(8)));

DEV float rcpf_(float x) { return __builtin_amdgcn_rcpf(x); }
DEV float rsqf_(float x) { return __builtin_amdgcn_rsqf(x); }

// tanh(a)/a for a >= 0
DEV float tanh_over_a_pos(float a) {
    const float e = __expf(-2.0f * a);
    return (1.0f - e) * rcpf_((1.0f + e) * fmaxf(a, 1e-20f));
}

// bf16 split helpers (RNE)
DEV unsigned short f2bf(float f) {
    unsigned int u = __float_as_uint(f);
    u = (u + 0x7FFFu + ((u >> 16) & 1u)) >> 16;
    return (unsigned short)u;
}
DEV float bf2f(unsigned short h) { return __uint_as_float(((unsigned int)h) << 16); }

// Packed panel layout (exact LDS image; staging is a linear copy):
//   pack[kb][row][slot], kb = K-tile (32 K-elems), slot = 16B chunk 0..7.
//   chunks 0-3 = hi k-sub 0..3, 4-7 = lo. Stored slot = chunk ^ (row & 7).
DEV void write_packed_row(unsigned short* pack, size_t nrow, int row,
                          int lane, ushort8v hi, ushort8v lo)
{
    const int kb  = lane >> 2;
    const int cch = lane & 3;
    const int rx  = row & 7;
    unsigned short* dst = pack + ((size_t)kb * nrow + row) * 64;   // 128B rows
    *(ushort8v*)(dst + ((cch ^ rx) * 8))       = hi;
    *(ushort8v*)(dst + (((cch + 4) ^ rx) * 8)) = lo;
}

// ---------------------------------------------------------------------------
// Merged prep kernel: 2 rows/wave (R9 structure) + FORCED LOAD HOIST.
// R9's VGPR_Count=44 proved the compiler sank the 20 float4 loads into
// ~4-6 sequential load->wait->compute rounds (80 VGPRs are needed to hold
// them); each round pays full memory latency that 3.5 waves/SIMD can't hide
// (VALUBusy 20%, HBM 25%, occ 45% -- nothing saturated). sched_barrier(0)
// is a hard fence: all loads must be ISSUED before any compute is scheduled,
// collapsing ~6 memory rounds to 1. __launch_bounds__(256,2) grants the
// VGPR budget (~150 needed, cap 256).
// ---------------------------------------------------------------------------
__global__ __launch_bounds__(256, 2)
void prep_kernel(const float* __restrict__ head,
                 const float* __restrict__ rel,
                 const float* __restrict__ rel_diag,
                 const float* __restrict__ curvature,
                 const float* __restrict__ context,
                 const float* __restrict__ scale_p,
                 const float* __restrict__ tail,
                 unsigned short* __restrict__ packA,
                 unsigned short* __restrict__ packB,
                 float* __restrict__ row_x2,
                 float* __restrict__ row_c,
                 float* __restrict__ row_sc,
                 float* __restrict__ vnorm,
                 int B, int T)
{
    const int lane = threadIdx.x & 63;
    const int base = lane * 8;
    const int wid  = blockIdx.x * 4 + (threadIdx.x >> 6);
    const int r0   = wid * 2;                       // first of the row pair

    if (r0 >= B) {
        // ---- tail path: 2 rows, loads hoisted + fenced ----
        const int tr = r0 - B;
        float v[2][8];
#pragma unroll
        for (int rr = 0; rr < 2; ++rr) {
            const size_t off = (size_t)(tr + rr) * D + base;
            *(float4*)&v[rr][0] = *(const float4*)(tail + off);
            *(float4*)&v[rr][4] = *(const float4*)(tail + off + 4);
        }
        __builtin_amdgcn_sched_barrier(0);   // pin: all loads issued first
        float s[2] = {0.f, 0.f};
        ushort8v hi[2], lo[2];
#pragma unroll
        for (int rr = 0; rr < 2; ++rr)
#pragma unroll
            for (int e = 0; e < 8; ++e) {
                s[rr] += v[rr][e] * v[rr][e];
                const unsigned short hb_ = f2bf(v[rr][e]);
                hi[rr][e] = hb_;
                lo[rr][e] = f2bf(v[rr][e] - bf2f(hb_));
            }
#pragma unroll
        for (int o = 32; o > 0; o >>= 1)
#pragma unroll
            for (int rr = 0; rr < 2; ++rr)
                s[rr] += __shfl_xor(s[rr], o, 64);
#pragma unroll
        for (int rr = 0; rr < 2; ++rr) {
            write_packed_row(packB, (size_t)T, tr + rr, lane, hi[rr], lo[rr]);
            if (lane == 0) vnorm[tr + rr] = sqrtf(s[rr]);
        }
        return;
    }

    // ---- head path: 2 rows, ALL loads issued up front, then fenced ----
    float hv[2][8], rv[2][8], gv[2][8], fv[2][8], cxv[2][8];
    float cu[2];
#pragma unroll
    for (int rr = 0; rr < 2; ++rr) {
        const size_t roff = (size_t)(r0 + rr) * D + base;
        const size_t doff = (size_t)(r0 + rr) * 2 * D + base;
        *(float4*)&hv[rr][0]  = *(const float4*)(head + roff);
        *(float4*)&hv[rr][4]  = *(const float4*)(head + roff + 4);
        *(float4*)&rv[rr][0]  = *(const float4*)(rel + roff);
        *(float4*)&rv[rr][4]  = *(const float4*)(rel + roff + 4);
        *(float4*)&gv[rr][0]  = *(const float4*)(rel_diag + doff);
        *(float4*)&gv[rr][4]  = *(const float4*)(rel_diag + doff + 4);
        *(float4*)&fv[rr][0]  = *(const float4*)(rel_diag + doff + D);
        *(float4*)&fv[rr][4]  = *(const float4*)(rel_diag + doff + D + 4);
        *(float4*)&cxv[rr][0] = *(const float4*)(context + roff);
        *(float4*)&cxv[rr][4] = *(const float4*)(context + roff + 4);
        cu[rr] = curvature[r0 + rr];
    }
    const float sc = scale_p[0];
    __builtin_amdgcn_sched_barrier(0);   // pin: all 22 loads issued first

    float rq[2][8], rf[2][8];
#pragma unroll
    for (int rr = 0; rr < 2; ++rr)
#pragma unroll
        for (int p = 0; p < 4; ++p) {
            const float x0 = hv[rr][2*p], x1 = hv[rr][2*p+1];
            float g0 = gv[rr][2*p], g1 = gv[rr][2*p+1];
            const float gi = rsqf_(fmaxf(g0*g0 + g1*g1, 1e-30f));
            g0 *= gi; g1 *= gi;
            rq[rr][2*p]   = g0*x0 - g1*x1;       // rotation
            rq[rr][2*p+1] = g0*x1 + g1*x0;
            float f0 = fv[rr][2*p], f1 = fv[rr][2*p+1];
            const float fi = rsqf_(fmaxf(f0*f0 + f1*f1, 1e-30f));
            f0 *= fi; f1 *= fi;
            rf[rr][2*p]   = f0*x0 + f1*x1;       // reflection
            rf[rr][2*p+1] = f1*x0 - f0*x1;
        }

    float s[2][8];
#pragma unroll
    for (int rr = 0; rr < 2; ++rr) {
#pragma unroll
        for (int k = 0; k < 8; ++k) s[rr][k] = 0.f;
#pragma unroll
        for (int e = 0; e < 8; ++e) {
            s[rr][0] += cxv[rr][e]*rf[rr][e];   s[rr][1] += cxv[rr][e]*rq[rr][e];
            s[rr][2] += rv[rr][e]*rv[rr][e];    s[rr][3] += rf[rr][e]*rv[rr][e];
            s[rr][4] += rq[rr][e]*rv[rr][e];    s[rr][5] += rf[rr][e]*rf[rr][e];
            s[rr][6] += rq[rr][e]*rq[rr][e];    s[rr][7] += rf[rr][e]*rq[rr][e];
        }
    }
    // 16 interleaved butterfly chains
#pragma unroll
    for (int o = 32; o > 0; o >>= 1)
#pragma unroll
        for (int rr = 0; rr < 2; ++rr)
#pragma unroll
            for (int k = 0; k < 8; ++k)
                s[rr][k] += __shfl_xor(s[rr][k], o, 64);

    float pre[2][8], r2p[2];
    float cS[2], sqcS[2];
#pragma unroll
    for (int rr = 0; rr < 2; ++rr) {
        const float c  = fmaxf(cu[rr], 0.0f) + __logf(1.0f + __expf(-fabsf(cu[rr])));
        const float sqc = sqrtf(c);
        cS[rr] = c; sqcS[rr] = sqc;

        const float a0 = s[rr][0] * sc, a1 = s[rr][1] * sc;
        const float mx = fmaxf(a0, a1);
        const float e0 = __expf(a0 - mx), e1 = __expf(a1 - mx);
        const float w0 = e0 * rcpf_(e0 + e1);
        const float w1 = 1.0f - w0;

        const float att2    = fmaxf(w0*w0*s[rr][5] + 2.0f*w0*w1*s[rr][7] + w1*w1*s[rr][6], 0.0f);
        const float attdrel = w0*s[rr][3] + w1*s[rr][4];
        const float u_att = fmaxf(sqrtf(att2), MIN_NORM);
        const float u_rel = fmaxf(sqrtf(s[rr][2]), MIN_NORM);

        const float kl = tanh_over_a_pos(sqcS[rr] * u_att);
        const float kr = tanh_over_a_pos(sqcS[rr] * u_rel);

        const float x2 = kl*kl*att2;
        const float y2 = kr*kr*s[rr][2];
        const float xy = kl*kr*attdrel;

        const float Am  = 1.0f + 2.0f*c*xy + c*y2;
        const float Bm  = 1.0f - c*x2;
        const float inv_den = rcpf_(fmaxf(1.0f + 2.0f*c*xy + c*c*x2*y2, MIN_NORM));

        r2p[rr] = 0.f;
#pragma unroll
        for (int e = 0; e < 8; ++e) {
            const float attq = w0*rf[rr][e] + w1*rq[rr][e];
            pre[rr][e] = (Am*kl*attq + Bm*kr*rv[rr][e]) * inv_den;
            r2p[rr] += pre[rr][e]*pre[rr][e];
        }
    }
    // interleaved reduce of the 2 projection norms
#pragma unroll
    for (int o = 32; o > 0; o >>= 1)
#pragma unroll
        for (int rr = 0; rr < 2; ++rr)
            r2p[rr] += __shfl_xor(r2p[rr], o, 64);

#pragma unroll
    for (int rr = 0; rr < 2; ++rr) {
        const float nrm  = fmaxf(sqrtf(r2p[rr]), MIN_NORM);
        const float maxn = (1.0f - BALL_EPS) * rcpf_(sqcS[rr]);
        const float psc  = (nrm > maxn) ? (maxn * rcpf_(nrm)) : 1.0f;

        ushort8v hi, lo;
#pragma unroll
        for (int e = 0; e < 8; ++e) {
            const float o = pre[rr][e] * psc;
            const unsigned short hb_ = f2bf(o);
            hi[e] = hb_;
            lo[e] = f2bf(o - bf2f(hb_));
        }
        write_packed_row(packA, (size_t)B, r0 + rr, lane, hi, lo);

        if (lane == 0) {
            row_x2[r0 + rr] = r2p[rr] * psc * psc;
            row_c[r0 + rr]  = cS[rr];
            row_sc[r0 + rr] = sqcS[rr];
        }
    }
}

// ---------------------------------------------------------------------------
// Kernel C (EXACT R9 revert -- best measured): 256x256 tile, 8 waves, BK=32
// hi|lo packed 128B rows, dbuf 128KB, ONE vmcnt(0)+barrier per K-step.
// ---------------------------------------------------------------------------
__global__ __launch_bounds__(512, 2)
void score_kernel(const unsigned short* __restrict__ packA,
                  const unsigned short* __restrict__ packB,
                  const float* __restrict__ vnorm,
                  const float* __restrict__ row_x2,
                  const float* __restrict__ row_c,
                  const float* __restrict__ row_sc,
                  const float* __restrict__ head_bias,
                  const float* __restrict__ tail_bias,
                  float* __restrict__ out,
                  int cs, int ns, int nrowA, int nrowB)
{
    extern __shared__ __align__(16) char smem[];   // 2 slots x (A 32KB | B 32KB)

    // XCD-aware remap: each XCD gets 32 contiguous blocks (= 2 whole batches).
    const int orig = blockIdx.x;
    const int wg = (orig & 7) * 32 + (orig >> 3);
    const int bz = wg >> 4;
    const int by = (wg >> 2) & 3;
    const int bx = wg & 3;
    const int m0 = by * 256;
    const int n0 = bx * 256;

    const int tid  = threadIdx.x;
    const int lane = tid & 63;
    const int w    = tid >> 6;
    const int wr   = w >> 2, wn = w & 3;          // 2x4 wave grid, 128x64 each
    const int lrow = lane & 15, lg = lane >> 4;

    f32x4 acc[8][4];
#pragma unroll
    for (int i = 0; i < 8; ++i)
#pragma unroll
        for (int j = 0; j < 4; ++j) acc[i][j] = f32x4{0.f, 0.f, 0.f, 0.f};

    // per-thread constant read bases: row&7 == lrow&7 for all frags
    const int xr = (lg ^ (lrow & 7)) * 16;
    const int baseA = (wr * 128 + lrow) * 128 + xr;           // A frag m: +m*2048
    const int baseB = 32768 + (wn * 64 + lrow) * 128 + xr;    // B frag n: +n*2048
    // lo chunk = hi byte-offset ^ 64

    // stage addressing (linear 8KB chunks: 512 thr x 16B)
    const int s16 = (tid & 255) * 16;
    const int shi = tid >> 8;   // 0 or 1

    const char* gA = (const char*)packA + (size_t)(bz * cs + m0) * 128;
    const char* gB = (const char*)packB + (size_t)(bz * ns + n0) * 128;
    const size_t strA = (size_t)nrowA * 128;   // per-K-tile panel stride
    const size_t strB = (size_t)nrowB * 128;

#define GLL(srcp, dstp)                                                        \
    __builtin_amdgcn_global_load_lds(                                          \
        (const __attribute__((address_space(1))) unsigned int*)(srcp),         \
        (__attribute__((address_space(3))) unsigned int*)(dstp), 16, 0, 0)

    // one 8KB chunk: off0 + (tid&255)*16 + (tid>>8)*sstr  (same offset in LDS)
#define STAGE(dstbase, srcpanel, off0, sstr)                                   \
    do { const int o_ = (off0) + s16 + shi * (sstr);                           \
         GLL((srcpanel) + o_, (dstbase) + o_); } while (0)

    // full-tile stage: A panel (32KB) + B panel (32KB), 8 GLL per thread
#define STAGE_ALL(dstslot, srcA, srcB)                                         \
    do {                                                                       \
        STAGE(dstslot, srcA, 0, 4096);      STAGE(dstslot, srcA, 16384, 4096); \
        STAGE(dstslot, srcA, 8192, 4096);   STAGE(dstslot, srcA, 24576, 4096); \
        STAGE((dstslot)+32768, srcB, 0, 8192);                                 \
        STAGE((dstslot)+32768, srcB, 16384, 8192);                             \
        STAGE((dstslot)+32768, srcB, 4096, 8192);                              \
        STAGE((dstslot)+32768, srcB, 20480, 8192);                             \
    } while (0)

#define RD(p, off) (*(const short8v*)((p) + (off)))
#define MFMA_(A_, B_, C_) __builtin_amdgcn_mfma_f32_16x16x32_bf16(A_, B_, C_, 0, 0, 0)

    // one C-quadrant: 4 m-frags x 2 n-frags x 3 products = 24 MFMA
#define QUAD(MOFF, NOFF)                                                       \
    do {                                                                       \
        _Pragma("unroll") for (int mm = 0; mm < 4; ++mm)                       \
        _Pragma("unroll") for (int nn = 0; nn < 2; ++nn)                       \
            acc[(MOFF)+mm][(NOFF)+nn] = MFMA_(ah[mm], bh[(NOFF)+nn], acc[(MOFF)+mm][(NOFF)+nn]); \
        _Pragma("unroll") for (int mm = 0; mm < 4; ++mm)                       \
        _Pragma("unroll") for (int nn = 0; nn < 2; ++nn)                       \
            acc[(MOFF)+mm][(NOFF)+nn] = MFMA_(ah[mm], bl[(NOFF)+nn], acc[(MOFF)+mm][(NOFF)+nn]); \
        _Pragma("unroll") for (int mm = 0; mm < 4; ++mm)                       \
        _Pragma("unroll") for (int nn = 0; nn < 2; ++nn)                       \
            acc[(MOFF)+mm][(NOFF)+nn] = MFMA_(al[mm], bh[(NOFF)+nn], acc[(MOFF)+mm][(NOFF)+nn]); \
    } while (0)

#define BAR()   __builtin_amdgcn_s_barrier()
#define VM0()   asm volatile("s_waitcnt vmcnt(0)" ::: "memory")

    // ---- prologue: tile0 -> slot0 ----
    STAGE_ALL(smem, gA, gB);
    VM0();
    BAR();

    short8v ah[4], al[4], bh[4], bl[4];

#pragma unroll 1
    for (int t = 0; t < 16; ++t) {
        char* cur = smem + (t & 1) * 65536;          // holds tile t
        char* oth = smem + ((t + 1) & 1) * 65536;

        // stage tile t+1 first (max vmcnt cover under this step's compute)
        if (t < 15)
            STAGE_ALL(oth, gA + (size_t)(t + 1) * strA, gB + (size_t)(t + 1) * strB);

        // ---- full K-step compute: 16 ds_read + 96 MFMA, no barriers ----
        // q0: A0 x B0
#pragma unroll
        for (int m = 0; m < 4; ++m) {
            ah[m] = RD(cur, baseA + m * 2048);
            al[m] = RD(cur, (baseA ^ 64) + m * 2048);
        }
#pragma unroll
        for (int n = 0; n < 2; ++n) {
            bh[n] = RD(cur, baseB + n * 2048);
            bl[n] = RD(cur, (baseB ^ 64) + n * 2048);
        }
        QUAD(0, 0);
        // q1: A0 x B1
#pragma unroll
        for (int n = 2; n < 4; ++n) {
            bh[n] = RD(cur, baseB + n * 2048);
            bl[n] = RD(cur, (baseB ^ 64) + n * 2048);
        }
        QUAD(0, 2);
        // q2: A1 x B1
#pragma unroll
        for (int m = 0; m < 4; ++m) {
            ah[m] = RD(cur, baseA + 8192 + m * 2048);
            al[m] = RD(cur, (baseA ^ 64) + 8192 + m * 2048);
        }
        QUAD(4, 2);
        // q3: A1 x B0 (B0 still live)
        QUAD(4, 0);

        // single end-of-step sync: my 8 staging loads for t+1 have landed
        VM0();
        BAR();
    }

    // ---- fused hyperbolic-distance epilogue ----
    // C/D layout (m89-verified): col = lane&15, row = (lane>>4)*4 + q
    const int nbase = n0 + wn * 64 + lrow;
    float rvn[4], vnv[4], tb[4];
#pragma unroll
    for (int j = 0; j < 4; ++j) {
        const int gn = bz * ns + nbase + j * 16;
        const float vn = vnorm[gn];
        vnv[j] = vn;
        rvn[j] = 1.0f / vn;
        tb[j]  = tail_bias[gn];
    }
#pragma unroll
    for (int i = 0; i < 8; ++i) {
#pragma unroll
        for (int q = 0; q < 4; ++q) {
            const int gm = bz * cs + m0 + wr * 128 + i * 16 + lg * 4 + q;
            const float x2  = row_x2[gm];
            const float cc  = row_c[gm];
            const float scq = row_sc[gm];
            const float hb  = head_bias[gm];
            const float rscq = 1.0f / scq;
            float* orow = out + (size_t)gm * ns + nbase;
#pragma unroll
            for (int j = 0; j < 4; ++j) {
                const float xv = acc[i][j][q] * rvn[j];
                float xx = fminf(scq * vnv[j], 15.0f);           // x >= 0 always
                const float ey = __expf(2.0f * xx);
                const float g  = (1.0f - 2.0f / (ey + 1.0f)) * rscq;  // tanh/sqc
                const float c1 = 1.0f - 2.0f*cc*g*xv + cc*g*g;
                const float c2 = 1.0f - cc*x2;
                const float num = sqrtf(fmaxf(c1*c1*x2 + c2*c2*g*g - 2.0f*c1*c2*g*xv, 0.0f));
                const float den = fmaxf(1.0f - 2.0f*cc*g*xv + cc*cc*g*g*x2, MIN_NORM);
                float tt = scq * num * __builtin_amdgcn_rcpf(den);
                tt = fminf(tt, 1.0f - 1e-5f);                    // t >= 0 always
                const float ath = 0.5f * __logf((1.0f + tt) * __builtin_amdgcn_rcpf(1.0f - tt));
                const float dist = 2.0f * rscq * ath;
                orow[j * 16] = -dist * dist + hb + tb[j];
            }
        }
    }
#undef GLL
#undef STAGE
#undef STAGE_ALL
#undef RD
#undef MFMA_
#undef QUAD
#undef BAR
#undef VM0
}

// ---------------------------------------------------------------------------
extern "C" void kernel_launch(void* const* d_in, const int* in_sizes, int n_in,
                              void* d_out, int out_size, void* d_ws, size_t ws_size,
                              hipStream_t stream)
{
    const float* head      = (const float*)d_in[0];
    const float* head_bias = (const float*)d_in[1];
    const float* rel       = (const float*)d_in[2];
    const float* rel_diag  = (const float*)d_in[3];
    const float* curvature = (const float*)d_in[4];
    const float* context   = (const float*)d_in[5];
    const float* scale     = (const float*)d_in[6];
    const float* tail      = (const float*)d_in[7];
    const float* tail_bias = (const float*)d_in[8];

    const int B  = in_sizes[1];        // 16384
    const int T  = in_sizes[8];        // 16384
    const int ns = out_size / B;       // 1024
    const int nc = T / ns;             // 16
    const int cs = B / nc;             // 1024

    // ws layout: packA (16*B*64 us = 32MB) | packB (32MB) | f32 scalars
    unsigned short* packA = (unsigned short*)d_ws;
    unsigned short* packB = packA + (size_t)16 * B * 64;
    float* row_x2 = (float*)(packB + (size_t)16 * T * 64);
    float* row_c  = row_x2 + B;
    float* row_sc = row_c + B;
    float* vnormb = row_sc + B;

    prep_kernel<<<(B + T) / 8, 256, 0, stream>>>(head, rel, rel_diag, curvature,
                                                 context, scale, tail, packA, packB,
                                                 row_x2, row_c, row_sc, vnormb, B, T);

    (void)hipFuncSetAttribute((const void*)score_kernel,
                              hipFuncAttributeMaxDynamicSharedMemorySize, 131072);
    const int nblk = (ns / 256) * (cs / 256) * nc;   // 256
    score_kernel<<<nblk, 512, 131072, stream>>>(packA, packB, vnormb, row_x2, row_c,
                                                row_sc, head_bias, tail_bias,
                                                (float*)d_out, cs, ns, B, T);
}